// Round 12
// baseline (1753.751 us; speedup 1.0000x reference)
//
#include <hip/hip_runtime.h>

constexpr int C = 1024, H = 256, V = 10000, K = 32, B = 8, T = 256, K1K = 65;
constexpr int DB = 32;            // blocks per domain
constexpr int NB = 4;             // batches per block (latency-hiding interleave)
constexpr int GSCAN = (B / NB) * DB;  // 64
constexpr float LV = 9.210340371976184f;  // ln(10000)
constexpr unsigned SENT = 0x80000000u;    // -0.0f: u values are >0, sign bit never set

#define DEV static __device__ __forceinline__

typedef float f4 __attribute__((ext_vector_type(4)));

DEV void gstore(float* p, float v) {
  __hip_atomic_store((unsigned*)p, __float_as_uint(v), __ATOMIC_RELAXED, __HIP_MEMORY_SCOPE_AGENT);
}
DEV float gload(const float* p) {
  return __uint_as_float(__hip_atomic_load((unsigned*)p, __ATOMIC_RELAXED, __HIP_MEMORY_SCOPE_AGENT));
}

// ---------- fused pre-kernel ----------
// bid 0..15: sentinel-init pay; 16: start; 17..80: term MLP (16 rows); 81..208: trans (8 rows)
__global__ void __launch_bounds__(256) k_pre(
    const float* __restrict__ semb, const float* __restrict__ linW, const float* __restrict__ linb,
    const float* __restrict__ srW1, const float* __restrict__ srb1,
    const float* __restrict__ srW2, const float* __restrict__ srb2,
    const float* __restrict__ nse, const float* __restrict__ se,
    const float* __restrict__ pre, const float* __restrict__ trW1, const float* __restrict__ trb1,
    const float* __restrict__ trW2, const float* __restrict__ trb2,
    const float* __restrict__ band,
    float* __restrict__ pay, float* __restrict__ startv,
    float* __restrict__ ft, float* __restrict__ PT) {
  __shared__ float smem[10504];  // 42 KB max across branches
  const int bid = blockIdx.x, tid = threadIdx.x;

  if (bid < 16) {  // sentinel-init 4 payload buffers: 4*B*C dwords
    unsigned* p = (unsigned*)pay;
    #pragma unroll
    for (int k = 0; k < 8; ++k) p[bid * 2048 + k * 256 + tid] = SENT;
    return;
  }

  if (bid == 16) {  // start vector: MLP + log_softmax over C
    float* sa = smem;
    float* fx = smem + 256;
    float* hh = smem + 512;
    float* sl = smem + 768;
    float* red = smem + 1792;
    sa[tid] = semb[tid];
    __syncthreads();
    float acc = linb[tid];
    for (int h = 0; h < H; ++h) acc += sa[h] * linW[tid * H + h];
    fx[tid] = acc;
    __syncthreads();
    for (int l = 0; l < 2; ++l) {
      float a1 = srb1[l * H + tid];
      const float* w1 = srW1 + (size_t)l * H * H + (size_t)tid * H;
      for (int h = 0; h < H; ++h) a1 += fx[h] * w1[h];
      hh[tid] = fmaxf(a1, 0.f);
      __syncthreads();
      float a2 = srb2[l * H + tid];
      const float* w2 = srW2 + (size_t)l * H * H + (size_t)tid * H;
      for (int h = 0; h < H; ++h) a2 += hh[h] * w2[h];
      __syncthreads();
      fx[tid] += fmaxf(a2, 0.f);
      __syncthreads();
    }
    for (int q = 0; q < 4; ++q) {
      int c = q * 256 + tid;
      const float* nr = nse + (size_t)c * H;
      float s = 0.f;
      for (int h = 0; h < H; ++h) s += fx[h] * nr[h];
      sl[c] = s;
    }
    __syncthreads();
    // logits are O(0.1): sum-only logsumexp is exact enough (no max pass)
    float s = 0.f;
    for (int q = 0; q < 4; ++q) s += __expf(sl[q * 256 + tid]);
    red[tid] = s; __syncthreads();
    for (int off = 128; off > 0; off >>= 1) { if (tid < off) red[tid] += red[tid + off]; __syncthreads(); }
    float lse = __logf(red[0]);
    for (int q = 0; q < 4; ++q) { int c = q * 256 + tid; startv[c] = sl[c] - lse; }
    return;
  }

  if (bid < 81) {  // terminal MLP: 16 rows/block (64 blocks) — weights read once per 16 rows
    float* x = smem;          // 16*256
    float* hh = smem + 4096;  // 16*256
    int r0 = (bid - 17) * 16;
    for (int r = 0; r < 16; ++r) x[r * 256 + tid] = pre[(size_t)(r0 + r) * H + tid];
    __syncthreads();
    for (int l = 0; l < 2; ++l) {
      {
        const f4* w = (const f4*)(trW1 + (size_t)l * H * H + (size_t)tid * H);
        float a[16];
        #pragma unroll
        for (int r = 0; r < 16; ++r) a[r] = 0.f;
        for (int h4 = 0; h4 < H / 4; ++h4) {
          f4 wv = w[h4];
          #pragma unroll
          for (int r = 0; r < 16; ++r) {
            f4 xv = *(const f4*)&x[r * 256 + h4 * 4];
            a[r] += wv.x * xv.x + wv.y * xv.y + wv.z * xv.z + wv.w * xv.w;
          }
        }
        float bb = trb1[l * H + tid];
        #pragma unroll
        for (int r = 0; r < 16; ++r) hh[r * 256 + tid] = fmaxf(a[r] + bb, 0.f);
      }
      __syncthreads();
      {
        const f4* w = (const f4*)(trW2 + (size_t)l * H * H + (size_t)tid * H);
        float a[16];
        #pragma unroll
        for (int r = 0; r < 16; ++r) a[r] = 0.f;
        for (int h4 = 0; h4 < H / 4; ++h4) {
          f4 wv = w[h4];
          #pragma unroll
          for (int r = 0; r < 16; ++r) {
            f4 xv = *(const f4*)&hh[r * 256 + h4 * 4];
            a[r] += wv.x * xv.x + wv.y * xv.y + wv.z * xv.z + wv.w * xv.w;
          }
        }
        float bb = trb2[l * H + tid];
        #pragma unroll
        for (int r = 0; r < 16; ++r) x[r * 256 + tid] += fmaxf(a[r] + bb, 0.f);
      }
      __syncthreads();
    }
    for (int r = 0; r < 16; ++r) ft[(size_t)(r0 + r) * H + tid] = x[r * 256 + tid];
    return;
  }

  // transition: 8 rows/block (128 blocks), max-free softmax, packed 32B PT stores
  {
    float* sv = smem;          // 8*256
    float* sl = smem + 2048;   // 8*1024
    float* pr = smem + 10240;  // 256
    float* iv = smem + 10496;  // 8
    int i0 = (bid - 81) * 8;
    for (int r = 0; r < 8; ++r) sv[r * 256 + tid] = se[(size_t)(i0 + r) * H + tid];
    __syncthreads();
    for (int jq = 0; jq < 4; ++jq) {
      int j = jq * 256 + tid;
      const f4* nr = (const f4*)(nse + (size_t)j * H);
      float a[8];
      #pragma unroll
      for (int r = 0; r < 8; ++r) a[r] = 0.f;
      for (int h4 = 0; h4 < H / 4; ++h4) {
        f4 nv = nr[h4];
        #pragma unroll
        for (int r = 0; r < 8; ++r) {
          f4 s4 = *(const f4*)&sv[r * 256 + h4 * 4];
          a[r] += nv.x * s4.x + nv.y * s4.y + nv.z * s4.z + nv.w * s4.w;
        }
      }
      #pragma unroll
      for (int r = 0; r < 8; ++r) sl[r * 1024 + j] = a[r];
    }
    __syncthreads();
    if (tid < K1K) {
      #pragma unroll
      for (int r = 0; r < 8; ++r) {
        int col = i0 + r + tid - K;
        if (col >= 0 && col < C) sl[r * 1024 + col] += band[(size_t)(i0 + r) * K1K + tid];
      }
    }
    __syncthreads();
    {  // exp + parallel row sums (logits O(0.1): no max needed)
      int row = tid >> 5, lane32 = tid & 31;
      float s = 0.f;
      for (int k = 0; k < 32; ++k) {
        int idx = row * 1024 + lane32 + k * 32;
        float e = __expf(sl[idx]);
        sl[idx] = e;
        s += e;
      }
      pr[tid] = s;
    }
    __syncthreads();
    if (tid < 8) {
      float s = 0.f;
      for (int k = 0; k < 32; ++k) s += pr[tid * 32 + k];
      iv[tid] = 1.f / s;
    }
    __syncthreads();
    for (int jq = 0; jq < 4; ++jq) {
      int j = jq * 256 + tid;
      f4 o0, o1;
      o0.x = sl[0 * 1024 + j] * iv[0]; o0.y = sl[1 * 1024 + j] * iv[1];
      o0.z = sl[2 * 1024 + j] * iv[2]; o0.w = sl[3 * 1024 + j] * iv[3];
      o1.x = sl[4 * 1024 + j] * iv[4]; o1.y = sl[5 * 1024 + j] * iv[5];
      o1.z = sl[6 * 1024 + j] * iv[6]; o1.w = sl[7 * 1024 + j] * iv[7];
      f4* dst = (f4*)(PT + (size_t)j * C + i0);
      dst[0] = o0; dst[1] = o1;  // 32B contiguous per thread
    }
  }
}

// ---------- emission denominators: sum-only, v-unrolled x4 (r8, proven) ----------
__global__ void __launch_bounds__(256) k_denom_part(
    const float* __restrict__ ft, const float* __restrict__ term, float* __restrict__ dpart) {
  constexpr int TJ = 16, VC = V / 8;  // 1250 = 4*256 + 226
  __shared__ float shs[TJ * 4];
  int tid = threadIdx.x, lane = tid & 63, w = tid >> 6;
  int jg = blockIdx.x >> 3, vc = blockIdx.x & 7;
  const f4* fb = (const f4*)(ft + (size_t)jg * TJ * H);
  float rs[TJ];
  #pragma unroll
  for (int r = 0; r < TJ; ++r) rs[r] = 0.f;
  int v0 = vc * VC;
  {
    const f4* t0 = (const f4*)(term + (size_t)(v0 + tid) * H);
    const f4* t1 = t0 + 256 * (H / 4);
    const f4* t2 = t1 + 256 * (H / 4);
    const f4* t3 = t2 + 256 * (H / 4);
    float a0[TJ], a1[TJ], a2[TJ], a3[TJ];
    #pragma unroll
    for (int r = 0; r < TJ; ++r) { a0[r] = 0.f; a1[r] = 0.f; a2[r] = 0.f; a3[r] = 0.f; }
    for (int h4 = 0; h4 < H / 4; ++h4) {
      f4 w0 = t0[h4], w1 = t1[h4], w2 = t2[h4], w3 = t3[h4];
      #pragma unroll
      for (int r = 0; r < TJ; ++r) {
        f4 f = fb[r * (H / 4) + h4];
        a0[r] += f.x * w0.x + f.y * w0.y + f.z * w0.z + f.w * w0.w;
        a1[r] += f.x * w1.x + f.y * w1.y + f.z * w1.z + f.w * w1.w;
        a2[r] += f.x * w2.x + f.y * w2.y + f.z * w2.z + f.w * w2.w;
        a3[r] += f.x * w3.x + f.y * w3.y + f.z * w3.z + f.w * w3.w;
      }
    }
    #pragma unroll
    for (int r = 0; r < TJ; ++r)
      rs[r] += __expf(a0[r]) + __expf(a1[r]) + __expf(a2[r]) + __expf(a3[r]);
  }
  if (tid < VC - 1024) {
    const f4* tt = (const f4*)(term + (size_t)(v0 + 1024 + tid) * H);
    float at[TJ];
    #pragma unroll
    for (int r = 0; r < TJ; ++r) at[r] = 0.f;
    for (int h4 = 0; h4 < H / 4; ++h4) {
      f4 wt = tt[h4];
      #pragma unroll
      for (int r = 0; r < TJ; ++r) {
        f4 f = fb[r * (H / 4) + h4];
        at[r] += f.x * wt.x + f.y * wt.y + f.z * wt.z + f.w * wt.w;
      }
    }
    #pragma unroll
    for (int r = 0; r < TJ; ++r) rs[r] += __expf(at[r]);
  }
  #pragma unroll
  for (int r = 0; r < TJ; ++r) {
    float s = rs[r];
    #pragma unroll
    for (int off = 32; off > 0; off >>= 1) s += __shfl_xor(s, off);
    if (lane == 0) shs[r * 4 + w] = s;
  }
  __syncthreads();
  if (tid < TJ) {
    float s = shs[tid * 4] + shs[tid * 4 + 1] + shs[tid * 4 + 2] + shs[tid * 4 + 3];
    dpart[(jg * TJ + tid) * 8 + vc] = s;
  }
}

// ---------- eem: 32 tokens/block staged in LDS, 512 j per block (128 blocks) ----------
__global__ void __launch_bounds__(256) k_eemit(
    const int* __restrict__ text, const float* __restrict__ ft,
    const float* __restrict__ dpart, const float* __restrict__ term,
    float* __restrict__ eem) {
  __shared__ float tk[32 * 256];  // 32 KB token rows
  __shared__ int ids[32];
  const int tid = threadIdx.x, bid = blockIdx.x;
  const int n0 = (bid >> 1) * 32, jh = bid & 1;
  if (tid < 32) {
    int n = n0 + tid;
    ids[tid] = text[(n & 7) * T + (n >> 3)];  // text[b*T + t], n = t*B+b
  }
  __syncthreads();
  for (int r = 0; r < 32; ++r) tk[r * 256 + tid] = term[(size_t)ids[r] * H + tid];
  __syncthreads();
  for (int q = 0; q < 2; ++q) {
    int j = jh * 512 + q * 256 + tid;
    const f4* fr = (const f4*)(ft + (size_t)j * H);
    float acc[32];
    #pragma unroll
    for (int r = 0; r < 32; ++r) acc[r] = 0.f;
    for (int h4 = 0; h4 < H / 4; ++h4) {
      f4 fv = fr[h4];
      #pragma unroll
      for (int r = 0; r < 32; ++r) {
        f4 tv = *(const f4*)&tk[r * 256 + h4 * 4];
        acc[r] += fv.x * tv.x + fv.y * tv.y + fv.z * tv.z + fv.w * tv.w;
      }
    }
    f4 d0 = *(const f4*)&dpart[j * 8];
    f4 d1 = *(const f4*)&dpart[j * 8 + 4];
    float dj = __logf(d0.x + d0.y + d0.z + d0.w + d1.x + d1.y + d1.z + d1.w);
    #pragma unroll
    for (int r = 0; r < 32; ++r)
      eem[(size_t)(n0 + r) * C + j] = __expf(acc[r] - dj + LV);
  }
}

// ---------- persistent scan: 4-way batch interleave (latency hiding) ----------
// 64 blocks = 2 domains x 32 blocks; each block serves 4 batches b0..b0+3 with the
// SAME P registers. Per iteration: 4 phases, each = r11's proven per-batch protocol.
// A batch's round trip (publish at iter t -> poll at iter t+1) spans a full
// iteration (~3us) >> LLC latency, so the exchange is latency-hidden.
#define PLOADA(k, ofs) \
  asm volatile("global_load_dwordx4 %0, %1, off offset:" #ofs : "=v"(p##k) : "v"(pb));
#define PDOT(k) { f4 x = *(const f4*)&us[ubo + (k) * 4]; facc += p##k * x; }

__global__ void __launch_bounds__(256, 1) k_scan(
    const float* __restrict__ PT, const float* __restrict__ eem,
    const float* __restrict__ startv, float* __restrict__ pay,
    float* __restrict__ umax, float* __restrict__ out) {
  __shared__ __align__(16) float us[8 * 132];  // phys(i) = (i>>7)*132 + (i&127), reused per phase
  __shared__ __align__(16) float wv[32];
  __shared__ float fred[256];
  const int tid = threadIdx.x, bid = blockIdx.x;
  const int g = bid & 1, blk = bid >> 1;  // 2 domains x 32 blocks
  const int b0 = g * NB;
  const int jloc = tid >> 3, s = tid & 7;
  const int myj = blk * 32 + jloc;
  const bool owner = (s == 0);

  // P slice via raw asm loads (validity enforced by first poll's vmcnt(0))
  const float* pb = PT + (size_t)myj * C + s * 128;
  f4 p0, p1, p2, p3, p4, p5, p6, p7, p8, p9, p10, p11, p12, p13, p14, p15;
  f4 p16, p17, p18, p19, p20, p21, p22, p23, p24, p25, p26, p27, p28, p29, p30, p31;
  PLOADA(0, 0)    PLOADA(1, 16)   PLOADA(2, 32)   PLOADA(3, 48)
  PLOADA(4, 64)   PLOADA(5, 80)   PLOADA(6, 96)   PLOADA(7, 112)
  PLOADA(8, 128)  PLOADA(9, 144)  PLOADA(10, 160) PLOADA(11, 176)
  PLOADA(12, 192) PLOADA(13, 208) PLOADA(14, 224) PLOADA(15, 240)
  PLOADA(16, 256) PLOADA(17, 272) PLOADA(18, 288) PLOADA(19, 304)
  PLOADA(20, 320) PLOADA(21, 336) PLOADA(22, 352) PLOADA(23, 368)
  PLOADA(24, 384) PLOADA(25, 400) PLOADA(26, 416) PLOADA(27, 432)
  PLOADA(28, 448) PLOADA(29, 464) PLOADA(30, 480) PLOADA(31, 496)

  float Sacc[NB];
  float em[NB];
  #pragma unroll
  for (int k = 0; k < NB; ++k) Sacc[k] = 0.f;

  // publish u_0 for all NB batches into buf 0 (sentinels from k_pre)
  if (owner) {
    float sv0 = __expf(startv[myj]);
    #pragma unroll
    for (int k = 0; k < NB; ++k)
      gstore(&pay[(size_t)(b0 + k) * C + myj], sv0 * eem[(size_t)(b0 + k) * C + myj]);
  }
  #pragma unroll
  for (int k = 0; k < NB; ++k)
    em[k] = owner ? eem[((size_t)B + (b0 + k)) * C + myj] : 0.f;  // prefetch t=1

  const int pi = tid * 4;
  const int ph = (pi >> 7) * 132 + (pi & 127);
  const int ubo = s * 132;

  for (int t = 1; t < T; ++t) {
    #pragma unroll
    for (int k = 0; k < NB; ++k) {
      const int b = b0 + k;
      // poll+stage u_{t-1}[b]: vmcnt(0) drains P loads (iter1), my clears, my publishes
      {
        const float* src = pay + (size_t)((t - 1) & 3) * (B * C) + (size_t)b * C + pi;
        f4 r;
        for (;;) {
          asm volatile("global_load_dwordx4 %0, %1, off sc0 sc1\n\ts_waitcnt vmcnt(0)"
                       : "=v"(r) : "v"(src) : "memory");
          unsigned bits = __float_as_uint(r.x) | __float_as_uint(r.y) |
                          __float_as_uint(r.z) | __float_as_uint(r.w);
          if (!(bits & 0x80000000u)) break;
          __builtin_amdgcn_s_sleep(1);
        }
        *(f4*)&us[ph] = r;
      }
      __syncthreads();

      float em_next = em[k];
      if (owner && t + 1 < T) em_next = eem[((size_t)(t + 1) * B + b) * C + myj];

      float imt = 1.f;
      if (owner && (t & 7) == 1 && t > 1) {
        float m = gload(&umax[((t - 1) >> 3) * 8 + b]);
        imt = 1.f / m;
        Sacc[k] += __logf(m);
      }

      // dot over my 128-i slice (u in LDS), reduce over 8 s-lanes
      f4 facc = {0.f, 0.f, 0.f, 0.f};
      PDOT(0) PDOT(1) PDOT(2) PDOT(3) PDOT(4) PDOT(5) PDOT(6) PDOT(7)
      PDOT(8) PDOT(9) PDOT(10) PDOT(11) PDOT(12) PDOT(13) PDOT(14) PDOT(15)
      PDOT(16) PDOT(17) PDOT(18) PDOT(19) PDOT(20) PDOT(21) PDOT(22) PDOT(23)
      PDOT(24) PDOT(25) PDOT(26) PDOT(27) PDOT(28) PDOT(29) PDOT(30) PDOT(31)
      float acc = facc.x + facc.y + facc.z + facc.w;
      acc += __shfl_xor(acc, 1);
      acc += __shfl_xor(acc, 2);
      acc += __shfl_xor(acc, 4);

      if (owner) wv[jloc] = acc * imt * em[k];
      __syncthreads();

      // sample-max every 8 steps (blk0): umax drained before this block's publish;
      // consumers gate on FULL u_t, so umax is visible when read at t+1
      if (blk == 0 && (t & 7) == 0) {
        if (tid == 0) {
          float m = wv[0];
          #pragma unroll
          for (int j2 = 1; j2 < 32; ++j2) m = fmaxf(m, wv[j2]);
          gstore(&umax[(t >> 3) * 8 + b], m);
          asm volatile("s_waitcnt vmcnt(0)" ::: "memory");
        }
        __syncthreads();
      }

      // packed publish: 8 lanes store the block's 128B chunk as dwordx4 granules
      if (tid < 8) {
        f4 pv4 = *(const f4*)&wv[tid * 4];
        float* dst = pay + (size_t)(t & 3) * (B * C) + (size_t)b * C + blk * 32 + tid * 4;
        asm volatile("global_store_dwordx4 %0, %1, off sc0 sc1" :: "v"(dst), "v"(pv4) : "memory");
      }

      // sentinel-clear buf (t+2)&3 of batch b (holds u_{t-2}: consumed by all, since
      // full u_{t-1} observed). Drained by this thread's next-phase poll vmcnt(0).
      if (tid < 8) {
        float* dst = pay + (size_t)((t + 2) & 3) * (B * C) + (size_t)b * C + blk * 32 + tid * 4;
        f4 sn;
        sn.x = sn.y = sn.z = sn.w = __uint_as_float(SENT);
        asm volatile("global_store_dwordx4 %0, %1, off sc0 sc1" :: "v"(dst), "v"(sn) : "memory");
      }
      em[k] = em_next;
    }
  }

  // final: blk0 of each domain polls u_{T-1} of each of its NB batches and reduces
  if (blk == 0) {
    #pragma unroll
    for (int kk = 0; kk < NB; ++kk) {
      const int b = b0 + kk;
      {
        const float* src = pay + (size_t)((T - 1) & 3) * (B * C) + (size_t)b * C + pi;
        f4 r;
        for (;;) {
          asm volatile("global_load_dwordx4 %0, %1, off sc0 sc1\n\ts_waitcnt vmcnt(0)"
                       : "=v"(r) : "v"(src) : "memory");
          unsigned bits = __float_as_uint(r.x) | __float_as_uint(r.y) |
                          __float_as_uint(r.z) | __float_as_uint(r.w);
          if (!(bits & 0x80000000u)) break;
          __builtin_amdgcn_s_sleep(1);
        }
        fred[tid] = r.x + r.y + r.z + r.w;
      }
      __syncthreads();
      for (int off = 128; off > 0; off >>= 1) {
        if (tid < off) fred[tid] += fred[tid + off];
        __syncthreads();
      }
      if (tid == 0) out[b] = -(float)T * LV + Sacc[kk] + __logf(fred[0]);
      __syncthreads();
    }
  }
}

extern "C" void kernel_launch(void* const* d_in, const int* in_sizes, int n_in,
                              void* d_out, int out_size, void* d_ws, size_t ws_size,
                              hipStream_t stream) {
  const int*   text  = (const int*)  d_in[0];
  const float* semb  = (const float*)d_in[1];
  const float* slinW = (const float*)d_in[2];
  const float* slinb = (const float*)d_in[3];
  const float* srW1  = (const float*)d_in[4];
  const float* srb1  = (const float*)d_in[5];
  const float* srW2  = (const float*)d_in[6];
  const float* srb2  = (const float*)d_in[7];
  const float* stemb = (const float*)d_in[8];
  const float* nse   = (const float*)d_in[9];
  const float* pre   = (const float*)d_in[10];
  const float* trW1  = (const float*)d_in[11];
  const float* trb1  = (const float*)d_in[12];
  const float* trW2  = (const float*)d_in[13];
  const float* trb2  = (const float*)d_in[14];
  const float* term  = (const float*)d_in[15];
  const float* band  = (const float*)d_in[16];

  float* ws     = (float*)d_ws;
  float* PT     = ws;                          // C*C (transposed P, fp32)
  float* eem    = PT + (size_t)C * C;          // T*B*C
  float* pay    = eem + (size_t)T * B * C;     // 4*B*C rotating sentinel buffers
  float* ftb    = pay + 4 * B * C;             // C*H
  float* startv = ftb + (size_t)C * H;         // C
  float* dpart  = startv + C;                  // C*8
  float* umax   = dpart + C * 8;               // 32*8

  k_pre<<<209, 256, 0, stream>>>(semb, slinW, slinb, srW1, srb1, srW2, srb2,
                                 nse, stemb, pre, trW1, trb1, trW2, trb2, band,
                                 pay, startv, ftb, PT);
  k_denom_part<<<(C / 16) * 8, 256, 0, stream>>>(ftb, term, dpart);
  k_eemit<<<128, 256, 0, stream>>>(text, ftb, dpart, term, eem);  // 64 tok-groups x 2 j-halves
  k_scan<<<GSCAN, 256, 0, stream>>>(PT, eem, startv, pay, umax, (float*)d_out);
}

// Round 13
// 994.820 us; speedup vs baseline: 1.7629x; 1.7629x over previous
//
#include <hip/hip_runtime.h>

constexpr int C = 1024, H = 256, V = 10000, K = 32, B = 8, T = 256, K1K = 65;
constexpr int DB = 32;            // blocks per batch domain
constexpr int GSCAN = B * DB;     // 256
constexpr float LV = 9.210340371976184f;  // ln(10000)
constexpr unsigned SENT = 0x80000000u;    // -0.0f: u values are >0, sign bit never set

#define DEV static __device__ __forceinline__

typedef float f4 __attribute__((ext_vector_type(4)));

DEV void gstore(float* p, float v) {
  __hip_atomic_store((unsigned*)p, __float_as_uint(v), __ATOMIC_RELAXED, __HIP_MEMORY_SCOPE_AGENT);
}
DEV float gload(const float* p) {
  return __uint_as_float(__hip_atomic_load((unsigned*)p, __ATOMIC_RELAXED, __HIP_MEMORY_SCOPE_AGENT));
}

// ---------- fused pre-kernel ----------
// bid 0..15: sentinel-init pay; 16: start; 17..80: term MLP (16 rows); 81..208: trans (8 rows)
__global__ void __launch_bounds__(256) k_pre(
    const float* __restrict__ semb, const float* __restrict__ linW, const float* __restrict__ linb,
    const float* __restrict__ srW1, const float* __restrict__ srb1,
    const float* __restrict__ srW2, const float* __restrict__ srb2,
    const float* __restrict__ nse, const float* __restrict__ se,
    const float* __restrict__ pre, const float* __restrict__ trW1, const float* __restrict__ trb1,
    const float* __restrict__ trW2, const float* __restrict__ trb2,
    const float* __restrict__ band,
    float* __restrict__ pay, float* __restrict__ startv,
    float* __restrict__ ft, float* __restrict__ PT) {
  __shared__ float smem[10504];  // 42 KB max across branches
  const int bid = blockIdx.x, tid = threadIdx.x;

  if (bid < 16) {  // sentinel-init 4 payload buffers: 4*B*C dwords
    unsigned* p = (unsigned*)pay;
    #pragma unroll
    for (int k = 0; k < 8; ++k) p[bid * 2048 + k * 256 + tid] = SENT;
    return;
  }

  if (bid == 16) {  // start vector: MLP + log_softmax over C
    float* sa = smem;
    float* fx = smem + 256;
    float* hh = smem + 512;
    float* sl = smem + 768;
    float* red = smem + 1792;
    sa[tid] = semb[tid];
    __syncthreads();
    float acc = linb[tid];
    for (int h = 0; h < H; ++h) acc += sa[h] * linW[tid * H + h];
    fx[tid] = acc;
    __syncthreads();
    for (int l = 0; l < 2; ++l) {
      float a1 = srb1[l * H + tid];
      const float* w1 = srW1 + (size_t)l * H * H + (size_t)tid * H;
      for (int h = 0; h < H; ++h) a1 += fx[h] * w1[h];
      hh[tid] = fmaxf(a1, 0.f);
      __syncthreads();
      float a2 = srb2[l * H + tid];
      const float* w2 = srW2 + (size_t)l * H * H + (size_t)tid * H;
      for (int h = 0; h < H; ++h) a2 += hh[h] * w2[h];
      __syncthreads();
      fx[tid] += fmaxf(a2, 0.f);
      __syncthreads();
    }
    for (int q = 0; q < 4; ++q) {
      int c = q * 256 + tid;
      const float* nr = nse + (size_t)c * H;
      float s = 0.f;
      for (int h = 0; h < H; ++h) s += fx[h] * nr[h];
      sl[c] = s;
    }
    __syncthreads();
    // logits are O(0.1): sum-only logsumexp is exact enough (no max pass)
    float s = 0.f;
    for (int q = 0; q < 4; ++q) s += __expf(sl[q * 256 + tid]);
    red[tid] = s; __syncthreads();
    for (int off = 128; off > 0; off >>= 1) { if (tid < off) red[tid] += red[tid + off]; __syncthreads(); }
    float lse = __logf(red[0]);
    for (int q = 0; q < 4; ++q) { int c = q * 256 + tid; startv[c] = sl[c] - lse; }
    return;
  }

  if (bid < 81) {  // terminal MLP: 16 rows/block (64 blocks) — weights read once per 16 rows
    float* x = smem;          // 16*256
    float* hh = smem + 4096;  // 16*256
    int r0 = (bid - 17) * 16;
    for (int r = 0; r < 16; ++r) x[r * 256 + tid] = pre[(size_t)(r0 + r) * H + tid];
    __syncthreads();
    for (int l = 0; l < 2; ++l) {
      {
        const f4* w = (const f4*)(trW1 + (size_t)l * H * H + (size_t)tid * H);
        float a[16];
        #pragma unroll
        for (int r = 0; r < 16; ++r) a[r] = 0.f;
        for (int h4 = 0; h4 < H / 4; ++h4) {
          f4 wv = w[h4];
          #pragma unroll
          for (int r = 0; r < 16; ++r) {
            f4 xv = *(const f4*)&x[r * 256 + h4 * 4];
            a[r] += wv.x * xv.x + wv.y * xv.y + wv.z * xv.z + wv.w * xv.w;
          }
        }
        float bb = trb1[l * H + tid];
        #pragma unroll
        for (int r = 0; r < 16; ++r) hh[r * 256 + tid] = fmaxf(a[r] + bb, 0.f);
      }
      __syncthreads();
      {
        const f4* w = (const f4*)(trW2 + (size_t)l * H * H + (size_t)tid * H);
        float a[16];
        #pragma unroll
        for (int r = 0; r < 16; ++r) a[r] = 0.f;
        for (int h4 = 0; h4 < H / 4; ++h4) {
          f4 wv = w[h4];
          #pragma unroll
          for (int r = 0; r < 16; ++r) {
            f4 xv = *(const f4*)&hh[r * 256 + h4 * 4];
            a[r] += wv.x * xv.x + wv.y * xv.y + wv.z * xv.z + wv.w * xv.w;
          }
        }
        float bb = trb2[l * H + tid];
        #pragma unroll
        for (int r = 0; r < 16; ++r) x[r * 256 + tid] += fmaxf(a[r] + bb, 0.f);
      }
      __syncthreads();
    }
    for (int r = 0; r < 16; ++r) ft[(size_t)(r0 + r) * H + tid] = x[r * 256 + tid];
    return;
  }

  // transition: 8 rows/block (128 blocks), max-free softmax, packed 32B PT stores
  {
    float* sv = smem;          // 8*256
    float* sl = smem + 2048;   // 8*1024
    float* pr = smem + 10240;  // 256
    float* iv = smem + 10496;  // 8
    int i0 = (bid - 81) * 8;
    for (int r = 0; r < 8; ++r) sv[r * 256 + tid] = se[(size_t)(i0 + r) * H + tid];
    __syncthreads();
    for (int jq = 0; jq < 4; ++jq) {
      int j = jq * 256 + tid;
      const f4* nr = (const f4*)(nse + (size_t)j * H);
      float a[8];
      #pragma unroll
      for (int r = 0; r < 8; ++r) a[r] = 0.f;
      for (int h4 = 0; h4 < H / 4; ++h4) {
        f4 nv = nr[h4];
        #pragma unroll
        for (int r = 0; r < 8; ++r) {
          f4 s4 = *(const f4*)&sv[r * 256 + h4 * 4];
          a[r] += nv.x * s4.x + nv.y * s4.y + nv.z * s4.z + nv.w * s4.w;
        }
      }
      #pragma unroll
      for (int r = 0; r < 8; ++r) sl[r * 1024 + j] = a[r];
    }
    __syncthreads();
    if (tid < K1K) {
      #pragma unroll
      for (int r = 0; r < 8; ++r) {
        int col = i0 + r + tid - K;
        if (col >= 0 && col < C) sl[r * 1024 + col] += band[(size_t)(i0 + r) * K1K + tid];
      }
    }
    __syncthreads();
    {  // exp + parallel row sums (logits O(0.1): no max needed)
      int row = tid >> 5, lane32 = tid & 31;
      float s = 0.f;
      for (int k = 0; k < 32; ++k) {
        int idx = row * 1024 + lane32 + k * 32;
        float e = __expf(sl[idx]);
        sl[idx] = e;
        s += e;
      }
      pr[tid] = s;
    }
    __syncthreads();
    if (tid < 8) {
      float s = 0.f;
      for (int k = 0; k < 32; ++k) s += pr[tid * 32 + k];
      iv[tid] = 1.f / s;
    }
    __syncthreads();
    for (int jq = 0; jq < 4; ++jq) {
      int j = jq * 256 + tid;
      f4 o0, o1;
      o0.x = sl[0 * 1024 + j] * iv[0]; o0.y = sl[1 * 1024 + j] * iv[1];
      o0.z = sl[2 * 1024 + j] * iv[2]; o0.w = sl[3 * 1024 + j] * iv[3];
      o1.x = sl[4 * 1024 + j] * iv[4]; o1.y = sl[5 * 1024 + j] * iv[5];
      o1.z = sl[6 * 1024 + j] * iv[6]; o1.w = sl[7 * 1024 + j] * iv[7];
      f4* dst = (f4*)(PT + (size_t)j * C + i0);
      dst[0] = o0; dst[1] = o1;  // 32B contiguous per thread
    }
  }
}

// ---------- emission denominators v2: LDS-staged ft tile, TJ=32, 256 blocks ----------
// term traffic halves vs r11 (512->256 blocks); LDS ft reads are wave-broadcast
// (all lanes same address -> conflict-free); FMA:VMEM = 128:1 (VALU-bound).
__global__ void __launch_bounds__(256) k_denom_part(
    const float* __restrict__ ft, const float* __restrict__ term, float* __restrict__ dpart) {
  constexpr int TJ = 32, VC = V / 8;  // 1250 = 4*256 + 226
  constexpr int RS = 264;             // padded row stride (16B-aligned)
  __shared__ float ftL[TJ * RS];      // 33.8 KB
  __shared__ float shs[TJ * 4];
  int tid = threadIdx.x, lane = tid & 63, w = tid >> 6;
  int jg = blockIdx.x >> 3, vc = blockIdx.x & 7;
  for (int r = 0; r < TJ; ++r) ftL[r * RS + tid] = ft[(size_t)(jg * TJ + r) * H + tid];
  __syncthreads();
  float rs[TJ];
  #pragma unroll
  for (int r = 0; r < TJ; ++r) rs[r] = 0.f;
  int v0 = vc * VC;
  for (int vstep = 0; vstep < 5; ++vstep) {
    if (vstep == 4 && tid >= VC - 1024) break;  // tail: 226 rows (no barriers below)
    const f4* tr = (const f4*)(term + (size_t)(v0 + vstep * 256 + tid) * H);
    float acc[TJ];
    #pragma unroll
    for (int r = 0; r < TJ; ++r) acc[r] = 0.f;
    for (int h4 = 0; h4 < H / 4; ++h4) {
      f4 tv = tr[h4];
      #pragma unroll
      for (int r = 0; r < TJ; ++r) {
        f4 f = *(const f4*)&ftL[r * RS + h4 * 4];
        acc[r] += tv.x * f.x + tv.y * f.y + tv.z * f.z + tv.w * f.w;
      }
    }
    #pragma unroll
    for (int r = 0; r < TJ; ++r) rs[r] += __expf(acc[r]);
  }
  #pragma unroll
  for (int r = 0; r < TJ; ++r) {
    float s = rs[r];
    #pragma unroll
    for (int off = 32; off > 0; off >>= 1) s += __shfl_xor(s, off);
    if (lane == 0) shs[r * 4 + w] = s;
  }
  __syncthreads();
  if (tid < TJ) {
    float s = shs[tid * 4] + shs[tid * 4 + 1] + shs[tid * 4 + 2] + shs[tid * 4 + 3];
    dpart[(jg * TJ + tid) * 8 + vc] = s;
  }
}

// ---------- eem: 32 tokens/block staged in LDS, 512 j per block (128 blocks) ----------
__global__ void __launch_bounds__(256) k_eemit(
    const int* __restrict__ text, const float* __restrict__ ft,
    const float* __restrict__ dpart, const float* __restrict__ term,
    float* __restrict__ eem) {
  __shared__ float tk[32 * 256];  // 32 KB token rows
  __shared__ int ids[32];
  const int tid = threadIdx.x, bid = blockIdx.x;
  const int n0 = (bid >> 1) * 32, jh = bid & 1;
  if (tid < 32) {
    int n = n0 + tid;
    ids[tid] = text[(n & 7) * T + (n >> 3)];  // text[b*T + t], n = t*B+b
  }
  __syncthreads();
  for (int r = 0; r < 32; ++r) tk[r * 256 + tid] = term[(size_t)ids[r] * H + tid];
  __syncthreads();
  for (int q = 0; q < 2; ++q) {
    int j = jh * 512 + q * 256 + tid;
    const f4* fr = (const f4*)(ft + (size_t)j * H);
    float acc[32];
    #pragma unroll
    for (int r = 0; r < 32; ++r) acc[r] = 0.f;
    for (int h4 = 0; h4 < H / 4; ++h4) {
      f4 fv = fr[h4];
      #pragma unroll
      for (int r = 0; r < 32; ++r) {
        f4 tv = *(const f4*)&tk[r * 256 + h4 * 4];
        acc[r] += fv.x * tv.x + fv.y * tv.y + fv.z * tv.z + fv.w * tv.w;
      }
    }
    f4 d0 = *(const f4*)&dpart[j * 8];
    f4 d1 = *(const f4*)&dpart[j * 8 + 4];
    float dj = __logf(d0.x + d0.y + d0.z + d0.w + d1.x + d1.y + d1.z + d1.w);
    #pragma unroll
    for (int r = 0; r < 32; ++r)
      eem[(size_t)(n0 + r) * C + j] = __expf(acc[r] - dj + LV);
  }
}

// ---------- persistent scan (r11 proven): bid-based domains, packed publish,
// clears retargeted to buf (t+2)&3 with a 2-step safety margin ----------
#define PLOADA(k, ofs) \
  asm volatile("global_load_dwordx4 %0, %1, off offset:" #ofs : "=v"(p##k) : "v"(pb));
#define PDOT(k) { f4 x = *(const f4*)&us[ubo + (k) * 4]; facc += p##k * x; }

__global__ void __launch_bounds__(256, 1) k_scan(
    const float* __restrict__ PT, const float* __restrict__ eem,
    const float* __restrict__ startv, float* __restrict__ pay,
    float* __restrict__ umax, float* __restrict__ out) {
  __shared__ __align__(16) float us[8 * 132];  // phys(i) = (i>>7)*132 + (i&127)
  __shared__ __align__(16) float wv[32];
  __shared__ float fred[256];
  const int tid = threadIdx.x, bid = blockIdx.x;
  const int b = bid & 7, blk = bid >> 3;
  const int jloc = tid >> 3, s = tid & 7;
  const int myj = blk * 32 + jloc;
  const bool owner = (s == 0);

  // P slice via raw asm loads (validity enforced by first poll's vmcnt(0))
  const float* pb = PT + (size_t)myj * C + s * 128;
  f4 p0, p1, p2, p3, p4, p5, p6, p7, p8, p9, p10, p11, p12, p13, p14, p15;
  f4 p16, p17, p18, p19, p20, p21, p22, p23, p24, p25, p26, p27, p28, p29, p30, p31;
  PLOADA(0, 0)    PLOADA(1, 16)   PLOADA(2, 32)   PLOADA(3, 48)
  PLOADA(4, 64)   PLOADA(5, 80)   PLOADA(6, 96)   PLOADA(7, 112)
  PLOADA(8, 128)  PLOADA(9, 144)  PLOADA(10, 160) PLOADA(11, 176)
  PLOADA(12, 192) PLOADA(13, 208) PLOADA(14, 224) PLOADA(15, 240)
  PLOADA(16, 256) PLOADA(17, 272) PLOADA(18, 288) PLOADA(19, 304)
  PLOADA(20, 320) PLOADA(21, 336) PLOADA(22, 352) PLOADA(23, 368)
  PLOADA(24, 384) PLOADA(25, 400) PLOADA(26, 416) PLOADA(27, 432)
  PLOADA(28, 448) PLOADA(29, 464) PLOADA(30, 480) PLOADA(31, 496)

  float Sacc = 0.f;

  // publish u_0 into buf 0 (sentinels from k_pre)
  if (owner) {
    float u0 = __expf(startv[myj]) * eem[(size_t)b * C + myj];
    gstore(&pay[(size_t)b * C + myj], u0);
  }
  float em = owner ? eem[((size_t)B + b) * C + myj] : 0.f;  // prefetch t=1

  const int pi = tid * 4;
  const int ph = (pi >> 7) * 132 + (pi & 127);
  const int ubo = s * 132;

  for (int t = 1; t < T; ++t) {
    // poll+stage u_{t-1}: vmcnt(0) drains P loads (iter1), my clears, my publishes
    {
      const float* src = pay + (size_t)((t - 1) & 3) * (B * C) + (size_t)b * C + pi;
      f4 r;
      for (;;) {
        asm volatile("global_load_dwordx4 %0, %1, off sc0 sc1\n\ts_waitcnt vmcnt(0)"
                     : "=v"(r) : "v"(src) : "memory");
        unsigned bits = __float_as_uint(r.x) | __float_as_uint(r.y) |
                        __float_as_uint(r.z) | __float_as_uint(r.w);
        if (!(bits & 0x80000000u)) break;
        __builtin_amdgcn_s_sleep(1);
      }
      *(f4*)&us[ph] = r;
    }
    __syncthreads();

    float em_next = em;
    if (owner && t + 1 < T) em_next = eem[((size_t)(t + 1) * B + b) * C + myj];

    float imt = 1.f;
    if (owner && (t & 7) == 1 && t > 1) {
      float m = gload(&umax[((t - 1) >> 3) * 8 + b]);
      imt = 1.f / m;
      Sacc += __logf(m);
    }

    // dot over my 128-i slice (u in LDS), reduce over 8 s-lanes
    f4 facc = {0.f, 0.f, 0.f, 0.f};
    PDOT(0) PDOT(1) PDOT(2) PDOT(3) PDOT(4) PDOT(5) PDOT(6) PDOT(7)
    PDOT(8) PDOT(9) PDOT(10) PDOT(11) PDOT(12) PDOT(13) PDOT(14) PDOT(15)
    PDOT(16) PDOT(17) PDOT(18) PDOT(19) PDOT(20) PDOT(21) PDOT(22) PDOT(23)
    PDOT(24) PDOT(25) PDOT(26) PDOT(27) PDOT(28) PDOT(29) PDOT(30) PDOT(31)
    float acc = facc.x + facc.y + facc.z + facc.w;
    acc += __shfl_xor(acc, 1);
    acc += __shfl_xor(acc, 2);
    acc += __shfl_xor(acc, 4);

    if (owner) wv[jloc] = acc * imt * em;
    __syncthreads();

    // sample-max every 8 steps (blk0): umax drained before this block's publish;
    // consumers gate on FULL u_t, so umax is visible when read at t+1
    if (blk == 0 && (t & 7) == 0) {
      if (tid == 0) {
        float m = wv[0];
        #pragma unroll
        for (int j2 = 1; j2 < 32; ++j2) m = fmaxf(m, wv[j2]);
        gstore(&umax[(t >> 3) * 8 + b], m);
        asm volatile("s_waitcnt vmcnt(0)" ::: "memory");
      }
      __syncthreads();
    }

    // packed publish: 8 lanes store the block's 128B chunk as dwordx4 granules
    if (tid < 8) {
      f4 pv4 = *(const f4*)&wv[tid * 4];
      float* dst = pay + (size_t)(t & 3) * (B * C) + (size_t)b * C + blk * 32 + tid * 4;
      asm volatile("global_store_dwordx4 %0, %1, off sc0 sc1" :: "v"(dst), "v"(pv4) : "memory");
    }

    // sentinel-clear buf (t+2)&3 (holds u_{t-2}: provably consumed by all since
    // full u_{t-1} was observed). 2-step margin before u_{t+2} publishes land here;
    // this block's own re-publish into it is ordered by two poll vmcnt(0)s.
    if (tid < 8) {
      float* dst = pay + (size_t)((t + 2) & 3) * (B * C) + (size_t)b * C + blk * 32 + tid * 4;
      f4 sn;
      sn.x = sn.y = sn.z = sn.w = __uint_as_float(SENT);
      asm volatile("global_store_dwordx4 %0, %1, off sc0 sc1" :: "v"(dst), "v"(sn) : "memory");
    }
    em = em_next;
  }

  // final: block 0 of each batch polls u_{T-1} and reduces
  if (blk == 0) {
    {
      const float* src = pay + (size_t)((T - 1) & 3) * (B * C) + (size_t)b * C + pi;
      f4 r;
      for (;;) {
        asm volatile("global_load_dwordx4 %0, %1, off sc0 sc1\n\ts_waitcnt vmcnt(0)"
                     : "=v"(r) : "v"(src) : "memory");
        unsigned bits = __float_as_uint(r.x) | __float_as_uint(r.y) |
                        __float_as_uint(r.z) | __float_as_uint(r.w);
        if (!(bits & 0x80000000u)) break;
        __builtin_amdgcn_s_sleep(1);
      }
      fred[tid] = r.x + r.y + r.z + r.w;
    }
    __syncthreads();
    for (int off = 128; off > 0; off >>= 1) {
      if (tid < off) fred[tid] += fred[tid + off];
      __syncthreads();
    }
    if (tid == 0) out[b] = -(float)T * LV + Sacc + __logf(fred[0]);
  }
}

extern "C" void kernel_launch(void* const* d_in, const int* in_sizes, int n_in,
                              void* d_out, int out_size, void* d_ws, size_t ws_size,
                              hipStream_t stream) {
  const int*   text  = (const int*)  d_in[0];
  const float* semb  = (const float*)d_in[1];
  const float* slinW = (const float*)d_in[2];
  const float* slinb = (const float*)d_in[3];
  const float* srW1  = (const float*)d_in[4];
  const float* srb1  = (const float*)d_in[5];
  const float* srW2  = (const float*)d_in[6];
  const float* srb2  = (const float*)d_in[7];
  const float* stemb = (const float*)d_in[8];
  const float* nse   = (const float*)d_in[9];
  const float* pre   = (const float*)d_in[10];
  const float* trW1  = (const float*)d_in[11];
  const float* trb1  = (const float*)d_in[12];
  const float* trW2  = (const float*)d_in[13];
  const float* trb2  = (const float*)d_in[14];
  const float* term  = (const float*)d_in[15];
  const float* band  = (const float*)d_in[16];

  float* ws     = (float*)d_ws;
  float* PT     = ws;                          // C*C (transposed P, fp32)
  float* eem    = PT + (size_t)C * C;          // T*B*C
  float* pay    = eem + (size_t)T * B * C;     // 4*B*C rotating sentinel buffers
  float* ftb    = pay + 4 * B * C;             // C*H
  float* startv = ftb + (size_t)C * H;         // C
  float* dpart  = startv + C;                  // C*8
  float* umax   = dpart + C * 8;               // 32*8

  k_pre<<<209, 256, 0, stream>>>(semb, slinW, slinb, srW1, srb1, srW2, srb2,
                                 nse, stemb, pre, trW1, trb1, trW2, trb2, band,
                                 pay, startv, ftb, PT);
  k_denom_part<<<(C / 32) * 8, 256, 0, stream>>>(ftb, term, dpart);
  k_eemit<<<128, 256, 0, stream>>>(text, ftb, dpart, term, eem);  // 64 tok-groups x 2 j-halves
  k_scan<<<GSCAN, 256, 0, stream>>>(PT, eem, startv, pay, umax, (float*)d_out);
}

// Round 14
// 866.260 us; speedup vs baseline: 2.0245x; 1.1484x over previous
//
#include <hip/hip_runtime.h>

constexpr int C = 1024, H = 256, V = 10000, K = 32, B = 8, T = 256, K1K = 65;
constexpr int DB = 32;            // blocks per batch domain
constexpr int GSCAN = B * DB;     // 256
constexpr float LV = 9.210340371976184f;  // ln(10000)
constexpr unsigned SENT = 0x80000000u;    // -0.0f: u values are >0, sign bit never set

#define DEV static __device__ __forceinline__

typedef float f4 __attribute__((ext_vector_type(4)));

DEV void gstore(float* p, float v) {
  __hip_atomic_store((unsigned*)p, __float_as_uint(v), __ATOMIC_RELAXED, __HIP_MEMORY_SCOPE_AGENT);
}
DEV float gload(const float* p) {
  return __uint_as_float(__hip_atomic_load((unsigned*)p, __ATOMIC_RELAXED, __HIP_MEMORY_SCOPE_AGENT));
}

// ---------- fused pre-kernel ----------
// bid 0..15: sentinel-init pay; 16: start; 17..80: term MLP (16 rows); 81..208: trans (8 rows)
__global__ void __launch_bounds__(256) k_pre(
    const float* __restrict__ semb, const float* __restrict__ linW, const float* __restrict__ linb,
    const float* __restrict__ srW1, const float* __restrict__ srb1,
    const float* __restrict__ srW2, const float* __restrict__ srb2,
    const float* __restrict__ nse, const float* __restrict__ se,
    const float* __restrict__ pre, const float* __restrict__ trW1, const float* __restrict__ trb1,
    const float* __restrict__ trW2, const float* __restrict__ trb2,
    const float* __restrict__ band,
    float* __restrict__ pay, float* __restrict__ startv,
    float* __restrict__ ft, float* __restrict__ PT) {
  __shared__ float smem[10504];  // 42 KB max across branches
  const int bid = blockIdx.x, tid = threadIdx.x;

  if (bid < 16) {  // sentinel-init 4 payload buffers: 4*B*C dwords
    unsigned* p = (unsigned*)pay;
    #pragma unroll
    for (int k = 0; k < 8; ++k) p[bid * 2048 + k * 256 + tid] = SENT;
    return;
  }

  if (bid == 16) {  // start vector: MLP + log_softmax over C
    float* sa = smem;
    float* fx = smem + 256;
    float* hh = smem + 512;
    float* sl = smem + 768;
    float* red = smem + 1792;
    sa[tid] = semb[tid];
    __syncthreads();
    float acc = linb[tid];
    for (int h = 0; h < H; ++h) acc += sa[h] * linW[tid * H + h];
    fx[tid] = acc;
    __syncthreads();
    for (int l = 0; l < 2; ++l) {
      float a1 = srb1[l * H + tid];
      const float* w1 = srW1 + (size_t)l * H * H + (size_t)tid * H;
      for (int h = 0; h < H; ++h) a1 += fx[h] * w1[h];
      hh[tid] = fmaxf(a1, 0.f);
      __syncthreads();
      float a2 = srb2[l * H + tid];
      const float* w2 = srW2 + (size_t)l * H * H + (size_t)tid * H;
      for (int h = 0; h < H; ++h) a2 += hh[h] * w2[h];
      __syncthreads();
      fx[tid] += fmaxf(a2, 0.f);
      __syncthreads();
    }
    for (int q = 0; q < 4; ++q) {
      int c = q * 256 + tid;
      const float* nr = nse + (size_t)c * H;
      float s = 0.f;
      for (int h = 0; h < H; ++h) s += fx[h] * nr[h];
      sl[c] = s;
    }
    __syncthreads();
    // logits are O(0.1): sum-only logsumexp is exact enough (no max pass)
    float s = 0.f;
    for (int q = 0; q < 4; ++q) s += __expf(sl[q * 256 + tid]);
    red[tid] = s; __syncthreads();
    for (int off = 128; off > 0; off >>= 1) { if (tid < off) red[tid] += red[tid + off]; __syncthreads(); }
    float lse = __logf(red[0]);
    for (int q = 0; q < 4; ++q) { int c = q * 256 + tid; startv[c] = sl[c] - lse; }
    return;
  }

  if (bid < 81) {  // terminal MLP: 16 rows/block (64 blocks) — weights read once per 16 rows
    float* x = smem;          // 16*256
    float* hh = smem + 4096;  // 16*256
    int r0 = (bid - 17) * 16;
    for (int r = 0; r < 16; ++r) x[r * 256 + tid] = pre[(size_t)(r0 + r) * H + tid];
    __syncthreads();
    for (int l = 0; l < 2; ++l) {
      {
        const f4* w = (const f4*)(trW1 + (size_t)l * H * H + (size_t)tid * H);
        float a[16];
        #pragma unroll
        for (int r = 0; r < 16; ++r) a[r] = 0.f;
        for (int h4 = 0; h4 < H / 4; ++h4) {
          f4 wv = w[h4];
          #pragma unroll
          for (int r = 0; r < 16; ++r) {
            f4 xv = *(const f4*)&x[r * 256 + h4 * 4];
            a[r] += wv.x * xv.x + wv.y * xv.y + wv.z * xv.z + wv.w * xv.w;
          }
        }
        float bb = trb1[l * H + tid];
        #pragma unroll
        for (int r = 0; r < 16; ++r) hh[r * 256 + tid] = fmaxf(a[r] + bb, 0.f);
      }
      __syncthreads();
      {
        const f4* w = (const f4*)(trW2 + (size_t)l * H * H + (size_t)tid * H);
        float a[16];
        #pragma unroll
        for (int r = 0; r < 16; ++r) a[r] = 0.f;
        for (int h4 = 0; h4 < H / 4; ++h4) {
          f4 wv = w[h4];
          #pragma unroll
          for (int r = 0; r < 16; ++r) {
            f4 xv = *(const f4*)&hh[r * 256 + h4 * 4];
            a[r] += wv.x * xv.x + wv.y * xv.y + wv.z * xv.z + wv.w * xv.w;
          }
        }
        float bb = trb2[l * H + tid];
        #pragma unroll
        for (int r = 0; r < 16; ++r) x[r * 256 + tid] += fmaxf(a[r] + bb, 0.f);
      }
      __syncthreads();
    }
    for (int r = 0; r < 16; ++r) ft[(size_t)(r0 + r) * H + tid] = x[r * 256 + tid];
    return;
  }

  // transition: 8 rows/block (128 blocks), max-free softmax, packed 32B PT stores
  {
    float* sv = smem;          // 8*256
    float* sl = smem + 2048;   // 8*1024
    float* pr = smem + 10240;  // 256
    float* iv = smem + 10496;  // 8
    int i0 = (bid - 81) * 8;
    for (int r = 0; r < 8; ++r) sv[r * 256 + tid] = se[(size_t)(i0 + r) * H + tid];
    __syncthreads();
    for (int jq = 0; jq < 4; ++jq) {
      int j = jq * 256 + tid;
      const f4* nr = (const f4*)(nse + (size_t)j * H);
      float a[8];
      #pragma unroll
      for (int r = 0; r < 8; ++r) a[r] = 0.f;
      for (int h4 = 0; h4 < H / 4; ++h4) {
        f4 nv = nr[h4];
        #pragma unroll
        for (int r = 0; r < 8; ++r) {
          f4 s4 = *(const f4*)&sv[r * 256 + h4 * 4];
          a[r] += nv.x * s4.x + nv.y * s4.y + nv.z * s4.z + nv.w * s4.w;
        }
      }
      #pragma unroll
      for (int r = 0; r < 8; ++r) sl[r * 1024 + j] = a[r];
    }
    __syncthreads();
    if (tid < K1K) {
      #pragma unroll
      for (int r = 0; r < 8; ++r) {
        int col = i0 + r + tid - K;
        if (col >= 0 && col < C) sl[r * 1024 + col] += band[(size_t)(i0 + r) * K1K + tid];
      }
    }
    __syncthreads();
    {  // exp + parallel row sums (logits O(0.1): no max needed)
      int row = tid >> 5, lane32 = tid & 31;
      float s = 0.f;
      for (int k = 0; k < 32; ++k) {
        int idx = row * 1024 + lane32 + k * 32;
        float e = __expf(sl[idx]);
        sl[idx] = e;
        s += e;
      }
      pr[tid] = s;
    }
    __syncthreads();
    if (tid < 8) {
      float s = 0.f;
      for (int k = 0; k < 32; ++k) s += pr[tid * 32 + k];
      iv[tid] = 1.f / s;
    }
    __syncthreads();
    for (int jq = 0; jq < 4; ++jq) {
      int j = jq * 256 + tid;
      f4 o0, o1;
      o0.x = sl[0 * 1024 + j] * iv[0]; o0.y = sl[1 * 1024 + j] * iv[1];
      o0.z = sl[2 * 1024 + j] * iv[2]; o0.w = sl[3 * 1024 + j] * iv[3];
      o1.x = sl[4 * 1024 + j] * iv[4]; o1.y = sl[5 * 1024 + j] * iv[5];
      o1.z = sl[6 * 1024 + j] * iv[6]; o1.w = sl[7 * 1024 + j] * iv[7];
      f4* dst = (f4*)(PT + (size_t)j * C + i0);
      dst[0] = o0; dst[1] = o1;  // 32B contiguous per thread
    }
  }
}

// ---------- emission denominators: sum-only, v-unrolled x4 (r11-proven; ft via L1) ----------
__global__ void __launch_bounds__(256) k_denom_part(
    const float* __restrict__ ft, const float* __restrict__ term, float* __restrict__ dpart) {
  constexpr int TJ = 16, VC = V / 8;  // 1250 = 4*256 + 226
  __shared__ float shs[TJ * 4];
  int tid = threadIdx.x, lane = tid & 63, w = tid >> 6;
  int jg = blockIdx.x >> 3, vc = blockIdx.x & 7;
  const f4* fb = (const f4*)(ft + (size_t)jg * TJ * H);
  float rs[TJ];
  #pragma unroll
  for (int r = 0; r < TJ; ++r) rs[r] = 0.f;
  int v0 = vc * VC;
  {
    const f4* t0 = (const f4*)(term + (size_t)(v0 + tid) * H);
    const f4* t1 = t0 + 256 * (H / 4);
    const f4* t2 = t1 + 256 * (H / 4);
    const f4* t3 = t2 + 256 * (H / 4);
    float a0[TJ], a1[TJ], a2[TJ], a3[TJ];
    #pragma unroll
    for (int r = 0; r < TJ; ++r) { a0[r] = 0.f; a1[r] = 0.f; a2[r] = 0.f; a3[r] = 0.f; }
    for (int h4 = 0; h4 < H / 4; ++h4) {
      f4 w0 = t0[h4], w1 = t1[h4], w2 = t2[h4], w3 = t3[h4];
      #pragma unroll
      for (int r = 0; r < TJ; ++r) {
        f4 f = fb[r * (H / 4) + h4];
        a0[r] += f.x * w0.x + f.y * w0.y + f.z * w0.z + f.w * w0.w;
        a1[r] += f.x * w1.x + f.y * w1.y + f.z * w1.z + f.w * w1.w;
        a2[r] += f.x * w2.x + f.y * w2.y + f.z * w2.z + f.w * w2.w;
        a3[r] += f.x * w3.x + f.y * w3.y + f.z * w3.z + f.w * w3.w;
      }
    }
    #pragma unroll
    for (int r = 0; r < TJ; ++r)
      rs[r] += __expf(a0[r]) + __expf(a1[r]) + __expf(a2[r]) + __expf(a3[r]);
  }
  if (tid < VC - 1024) {
    const f4* tt = (const f4*)(term + (size_t)(v0 + 1024 + tid) * H);
    float at[TJ];
    #pragma unroll
    for (int r = 0; r < TJ; ++r) at[r] = 0.f;
    for (int h4 = 0; h4 < H / 4; ++h4) {
      f4 wt = tt[h4];
      #pragma unroll
      for (int r = 0; r < TJ; ++r) {
        f4 f = fb[r * (H / 4) + h4];
        at[r] += f.x * wt.x + f.y * wt.y + f.z * wt.z + f.w * wt.w;
      }
    }
    #pragma unroll
    for (int r = 0; r < TJ; ++r) rs[r] += __expf(at[r]);
  }
  #pragma unroll
  for (int r = 0; r < TJ; ++r) {
    float s = rs[r];
    #pragma unroll
    for (int off = 32; off > 0; off >>= 1) s += __shfl_xor(s, off);
    if (lane == 0) shs[r * 4 + w] = s;
  }
  __syncthreads();
  if (tid < TJ) {
    float s = shs[tid * 4] + shs[tid * 4 + 1] + shs[tid * 4 + 2] + shs[tid * 4 + 3];
    dpart[(jg * TJ + tid) * 8 + vc] = s;
  }
}

// ---------- eem: 32 tokens/block staged in LDS, 512 j per block (128 blocks) ----------
__global__ void __launch_bounds__(256) k_eemit(
    const int* __restrict__ text, const float* __restrict__ ft,
    const float* __restrict__ dpart, const float* __restrict__ term,
    float* __restrict__ eem) {
  __shared__ float tk[32 * 256];  // 32 KB token rows
  __shared__ int ids[32];
  const int tid = threadIdx.x, bid = blockIdx.x;
  const int n0 = (bid >> 1) * 32, jh = bid & 1;
  if (tid < 32) {
    int n = n0 + tid;
    ids[tid] = text[(n & 7) * T + (n >> 3)];  // text[b*T + t], n = t*B+b
  }
  __syncthreads();
  for (int r = 0; r < 32; ++r) tk[r * 256 + tid] = term[(size_t)ids[r] * H + tid];
  __syncthreads();
  for (int q = 0; q < 2; ++q) {
    int j = jh * 512 + q * 256 + tid;
    const f4* fr = (const f4*)(ft + (size_t)j * H);
    float acc[32];
    #pragma unroll
    for (int r = 0; r < 32; ++r) acc[r] = 0.f;
    for (int h4 = 0; h4 < H / 4; ++h4) {
      f4 fv = fr[h4];
      #pragma unroll
      for (int r = 0; r < 32; ++r) {
        f4 tv = *(const f4*)&tk[r * 256 + h4 * 4];
        acc[r] += fv.x * tv.x + fv.y * tv.y + fv.z * tv.z + fv.w * tv.w;
      }
    }
    f4 d0 = *(const f4*)&dpart[j * 8];
    f4 d1 = *(const f4*)&dpart[j * 8 + 4];
    float dj = __logf(d0.x + d0.y + d0.z + d0.w + d1.x + d1.y + d1.z + d1.w);
    #pragma unroll
    for (int r = 0; r < 32; ++r)
      eem[(size_t)(n0 + r) * C + j] = __expf(acc[r] - dj + LV);
  }
}

// ---------- persistent scan (r11 proven): bid-based domains, packed publish,
// clears retargeted to buf (t+2)&3 with a 2-step safety margin ----------
#define PLOADA(k, ofs) \
  asm volatile("global_load_dwordx4 %0, %1, off offset:" #ofs : "=v"(p##k) : "v"(pb));
#define PDOT(k) { f4 x = *(const f4*)&us[ubo + (k) * 4]; facc += p##k * x; }

__global__ void __launch_bounds__(256, 1) k_scan(
    const float* __restrict__ PT, const float* __restrict__ eem,
    const float* __restrict__ startv, float* __restrict__ pay,
    float* __restrict__ umax, float* __restrict__ out) {
  __shared__ __align__(16) float us[8 * 132];  // phys(i) = (i>>7)*132 + (i&127)
  __shared__ __align__(16) float wv[32];
  __shared__ float fred[256];
  const int tid = threadIdx.x, bid = blockIdx.x;
  const int b = bid & 7, blk = bid >> 3;
  const int jloc = tid >> 3, s = tid & 7;
  const int myj = blk * 32 + jloc;
  const bool owner = (s == 0);

  // P slice via raw asm loads (validity enforced by first poll's vmcnt(0))
  const float* pb = PT + (size_t)myj * C + s * 128;
  f4 p0, p1, p2, p3, p4, p5, p6, p7, p8, p9, p10, p11, p12, p13, p14, p15;
  f4 p16, p17, p18, p19, p20, p21, p22, p23, p24, p25, p26, p27, p28, p29, p30, p31;
  PLOADA(0, 0)    PLOADA(1, 16)   PLOADA(2, 32)   PLOADA(3, 48)
  PLOADA(4, 64)   PLOADA(5, 80)   PLOADA(6, 96)   PLOADA(7, 112)
  PLOADA(8, 128)  PLOADA(9, 144)  PLOADA(10, 160) PLOADA(11, 176)
  PLOADA(12, 192) PLOADA(13, 208) PLOADA(14, 224) PLOADA(15, 240)
  PLOADA(16, 256) PLOADA(17, 272) PLOADA(18, 288) PLOADA(19, 304)
  PLOADA(20, 320) PLOADA(21, 336) PLOADA(22, 352) PLOADA(23, 368)
  PLOADA(24, 384) PLOADA(25, 400) PLOADA(26, 416) PLOADA(27, 432)
  PLOADA(28, 448) PLOADA(29, 464) PLOADA(30, 480) PLOADA(31, 496)

  float Sacc = 0.f;

  // publish u_0 into buf 0 (sentinels from k_pre)
  if (owner) {
    float u0 = __expf(startv[myj]) * eem[(size_t)b * C + myj];
    gstore(&pay[(size_t)b * C + myj], u0);
  }
  float em = owner ? eem[((size_t)B + b) * C + myj] : 0.f;  // prefetch t=1

  const int pi = tid * 4;
  const int ph = (pi >> 7) * 132 + (pi & 127);
  const int ubo = s * 132;

  for (int t = 1; t < T; ++t) {
    // poll+stage u_{t-1}: vmcnt(0) drains P loads (iter1), my clears, my publishes
    {
      const float* src = pay + (size_t)((t - 1) & 3) * (B * C) + (size_t)b * C + pi;
      f4 r;
      for (;;) {
        asm volatile("global_load_dwordx4 %0, %1, off sc0 sc1\n\ts_waitcnt vmcnt(0)"
                     : "=v"(r) : "v"(src) : "memory");
        unsigned bits = __float_as_uint(r.x) | __float_as_uint(r.y) |
                        __float_as_uint(r.z) | __float_as_uint(r.w);
        if (!(bits & 0x80000000u)) break;
        __builtin_amdgcn_s_sleep(1);
      }
      *(f4*)&us[ph] = r;
    }
    __syncthreads();

    float em_next = em;
    if (owner && t + 1 < T) em_next = eem[((size_t)(t + 1) * B + b) * C + myj];

    float imt = 1.f;
    if (owner && (t & 7) == 1 && t > 1) {
      float m = gload(&umax[((t - 1) >> 3) * 8 + b]);
      imt = 1.f / m;
      Sacc += __logf(m);
    }

    // dot over my 128-i slice (u in LDS), reduce over 8 s-lanes
    f4 facc = {0.f, 0.f, 0.f, 0.f};
    PDOT(0) PDOT(1) PDOT(2) PDOT(3) PDOT(4) PDOT(5) PDOT(6) PDOT(7)
    PDOT(8) PDOT(9) PDOT(10) PDOT(11) PDOT(12) PDOT(13) PDOT(14) PDOT(15)
    PDOT(16) PDOT(17) PDOT(18) PDOT(19) PDOT(20) PDOT(21) PDOT(22) PDOT(23)
    PDOT(24) PDOT(25) PDOT(26) PDOT(27) PDOT(28) PDOT(29) PDOT(30) PDOT(31)
    float acc = facc.x + facc.y + facc.z + facc.w;
    acc += __shfl_xor(acc, 1);
    acc += __shfl_xor(acc, 2);
    acc += __shfl_xor(acc, 4);

    if (owner) wv[jloc] = acc * imt * em;
    __syncthreads();

    // sample-max every 8 steps (blk0): umax drained before this block's publish;
    // consumers gate on FULL u_t, so umax is visible when read at t+1
    if (blk == 0 && (t & 7) == 0) {
      if (tid == 0) {
        float m = wv[0];
        #pragma unroll
        for (int j2 = 1; j2 < 32; ++j2) m = fmaxf(m, wv[j2]);
        gstore(&umax[(t >> 3) * 8 + b], m);
        asm volatile("s_waitcnt vmcnt(0)" ::: "memory");
      }
      __syncthreads();
    }

    // packed publish: 8 lanes store the block's 128B chunk as dwordx4 granules
    if (tid < 8) {
      f4 pv4 = *(const f4*)&wv[tid * 4];
      float* dst = pay + (size_t)(t & 3) * (B * C) + (size_t)b * C + blk * 32 + tid * 4;
      asm volatile("global_store_dwordx4 %0, %1, off sc0 sc1" :: "v"(dst), "v"(pv4) : "memory");
    }

    // sentinel-clear buf (t+2)&3 (holds u_{t-2}: provably consumed by all since
    // full u_{t-1} was observed). 2-step margin before u_{t+2} publishes land here;
    // this block's own re-publish into it is ordered by two poll vmcnt(0)s.
    if (tid < 8) {
      float* dst = pay + (size_t)((t + 2) & 3) * (B * C) + (size_t)b * C + blk * 32 + tid * 4;
      f4 sn;
      sn.x = sn.y = sn.z = sn.w = __uint_as_float(SENT);
      asm volatile("global_store_dwordx4 %0, %1, off sc0 sc1" :: "v"(dst), "v"(sn) : "memory");
    }
    em = em_next;
  }

  // final: block 0 of each batch polls u_{T-1} and reduces
  if (blk == 0) {
    {
      const float* src = pay + (size_t)((T - 1) & 3) * (B * C) + (size_t)b * C + pi;
      f4 r;
      for (;;) {
        asm volatile("global_load_dwordx4 %0, %1, off sc0 sc1\n\ts_waitcnt vmcnt(0)"
                     : "=v"(r) : "v"(src) : "memory");
        unsigned bits = __float_as_uint(r.x) | __float_as_uint(r.y) |
                        __float_as_uint(r.z) | __float_as_uint(r.w);
        if (!(bits & 0x80000000u)) break;
        __builtin_amdgcn_s_sleep(1);
      }
      fred[tid] = r.x + r.y + r.z + r.w;
    }
    __syncthreads();
    for (int off = 128; off > 0; off >>= 1) {
      if (tid < off) fred[tid] += fred[tid + off];
      __syncthreads();
    }
    if (tid == 0) out[b] = -(float)T * LV + Sacc + __logf(fred[0]);
  }
}

extern "C" void kernel_launch(void* const* d_in, const int* in_sizes, int n_in,
                              void* d_out, int out_size, void* d_ws, size_t ws_size,
                              hipStream_t stream) {
  const int*   text  = (const int*)  d_in[0];
  const float* semb  = (const float*)d_in[1];
  const float* slinW = (const float*)d_in[2];
  const float* slinb = (const float*)d_in[3];
  const float* srW1  = (const float*)d_in[4];
  const float* srb1  = (const float*)d_in[5];
  const float* srW2  = (const float*)d_in[6];
  const float* srb2  = (const float*)d_in[7];
  const float* stemb = (const float*)d_in[8];
  const float* nse   = (const float*)d_in[9];
  const float* pre   = (const float*)d_in[10];
  const float* trW1  = (const float*)d_in[11];
  const float* trb1  = (const float*)d_in[12];
  const float* trW2  = (const float*)d_in[13];
  const float* trb2  = (const float*)d_in[14];
  const float* term  = (const float*)d_in[15];
  const float* band  = (const float*)d_in[16];

  float* ws     = (float*)d_ws;
  float* PT     = ws;                          // C*C (transposed P, fp32)
  float* eem    = PT + (size_t)C * C;          // T*B*C
  float* pay    = eem + (size_t)T * B * C;     // 4*B*C rotating sentinel buffers
  float* ftb    = pay + 4 * B * C;             // C*H
  float* startv = ftb + (size_t)C * H;         // C
  float* dpart  = startv + C;                  // C*8
  float* umax   = dpart + C * 8;               // 32*8

  k_pre<<<209, 256, 0, stream>>>(semb, slinW, slinb, srW1, srb1, srW2, srb2,
                                 nse, stemb, pre, trW1, trb1, trW2, trb2, band,
                                 pay, startv, ftb, PT);
  k_denom_part<<<(C / 16) * 8, 256, 0, stream>>>(ftb, term, dpart);
  k_eemit<<<128, 256, 0, stream>>>(text, ftb, dpart, term, eem);  // 64 tok-groups x 2 j-halves
  k_scan<<<GSCAN, 256, 0, stream>>>(PT, eem, startv, pay, umax, (float*)d_out);
}